// Round 3
// baseline (615.444 us; speedup 1.0000x reference)
//
#include <hip/hip_runtime.h>
#include <hip/hip_bf16.h>
#include <cstdint>

#define N_NODES 100000
#define N_EDGES 1600000
#define FDIM 64
#define NPAIRS 200000
#define CAP 64

typedef __attribute__((ext_vector_type(8))) short short8;
typedef __attribute__((ext_vector_type(4))) float floatx4;

__device__ __forceinline__ float rlf(float v, int lane) {
    return __int_as_float(__builtin_amdgcn_readlane(__float_as_int(v), lane));
}

__device__ __forceinline__ unsigned short bf16_rtne(float f) {
    unsigned u = __float_as_uint(f);
    unsigned r = (u + 0x7fffu + ((u >> 16) & 1u)) >> 16;
    return (unsigned short)r;
}

// split f32 -> bf16 hi + bf16 lo (hi+lo reproduces f to ~2^-17 rel)
__device__ __forceinline__ void split8(const float* f, short8& hi, short8& lo) {
#pragma unroll
    for (int j = 0; j < 8; ++j) {
        unsigned short h = bf16_rtne(f[j]);
        hi[j] = (short)h;
        float hf = __uint_as_float(((unsigned)h) << 16);
        lo[j] = (short)bf16_rtne(f[j] - hf);
    }
}

// K0: h0 = 2*x (self term: (1+eps)*x + x inside agg), deg = 0
__global__ void k0_init(const float4* __restrict__ x4, float4* __restrict__ h04,
                        int* __restrict__ deg) {
    int i = blockIdx.x * blockDim.x + threadIdx.x;
    if (i < N_NODES * FDIM / 4) {
        float4 v = x4[i];
        v.x *= 2.f; v.y *= 2.f; v.z *= 2.f; v.w *= 2.f;
        h04[i] = v;
    }
    if (i < N_NODES) deg[i] = 0;
}

// K1: bucket edges by dst. Overflow (deg > CAP, prob ~2e-13 total but must be
// correct) falls back to direct atomics into h0 (initialized by K0).
__global__ void k1_fill(const int* __restrict__ src, const int* __restrict__ dst,
                        const float* __restrict__ x, float* __restrict__ h0,
                        int* __restrict__ deg, int* __restrict__ slots) {
    int e = blockIdx.x * blockDim.x + threadIdx.x;
    if (e >= N_EDGES) return;
    int s = src[e], d = dst[e];
    int pos = atomicAdd(&deg[d], 1);
    if (pos < CAP) {
        slots[(size_t)d * CAP + pos] = s;
    } else {
        const float* xr = x + (size_t)s * FDIM;
        float* hr = h0 + (size_t)d * FDIM;
        for (int f = 0; f < FDIM; ++f) atomicAdd(&hr[f], xr[f]);
    }
}

// K2: thread per (node, float4-chunk): 16 threads/node, int4 slot loads
// (broadcast within the node's 16 threads), 4 independent gathers in flight,
// no cross-lane ops in the dependent chain.
__global__ void __launch_bounds__(256) k2_agg(const float4* __restrict__ x4,
                       float4* __restrict__ h04,
                       const int* __restrict__ deg, const int* __restrict__ slots) {
    int gid = blockIdx.x * 256 + threadIdx.x;   // 1.6M = N*16
    int n = gid >> 4, fq = gid & 15;
    int dc = deg[n];
    if (dc > CAP) dc = CAP;
    const int4* srow = (const int4*)(slots + (size_t)n * CAP);
    float4 acc = h04[(size_t)n * 16 + fq];      // 2x + overflow atomics
    for (int i = 0; i < dc; i += 4) {
        int4 s4 = srow[i >> 2];
        float4 v = x4[(size_t)s4.x * 16 + fq];
        acc.x += v.x; acc.y += v.y; acc.z += v.z; acc.w += v.w;
        if (i + 1 < dc) {
            float4 u = x4[(size_t)s4.y * 16 + fq];
            acc.x += u.x; acc.y += u.y; acc.z += u.z; acc.w += u.w;
        }
        if (i + 2 < dc) {
            float4 u = x4[(size_t)s4.z * 16 + fq];
            acc.x += u.x; acc.y += u.y; acc.z += u.z; acc.w += u.w;
        }
        if (i + 3 < dc) {
            float4 u = x4[(size_t)s4.w * 16 + fq];
            acc.x += u.x; acc.y += u.y; acc.z += u.z; acc.w += u.w;
        }
    }
    h04[(size_t)n * 16 + fq] = acc;
}

// K3: node MLP, in-place, 8 nodes per wave (unchanged from R2).
__global__ void __launch_bounds__(256) k3_mlp(float* __restrict__ h,
                       const float* __restrict__ w1, const float* __restrict__ b1,
                       const float* __restrict__ w2, const float* __restrict__ b2) {
    __shared__ float w1s[64 * 64];
    __shared__ float w2s[64 * 64];
    int tid = threadIdx.x;
    const float4* w14 = (const float4*)w1;
    const float4* w24 = (const float4*)w2;
    float4* w1s4 = (float4*)w1s;
    float4* w2s4 = (float4*)w2s;
    for (int i = tid; i < 64 * 64 / 4; i += 256) {
        w1s4[i] = w14[i];
        w2s4[i] = w24[i];
    }
    __syncthreads();
    int lane = tid & 63;
    int wid = blockIdx.x * 4 + (tid >> 6);
    int n0 = wid * 8;
    float b1r = b1[lane], b2r = b2[lane];
    float v[8], acc[8];
#pragma unroll
    for (int u = 0; u < 8; ++u) {
        v[u] = h[(size_t)(n0 + u) * 64 + lane];
        acc[u] = b1r;
    }
#pragma unroll 8
    for (int k = 0; k < 64; ++k) {
        float w = w1s[k * 64 + lane];
#pragma unroll
        for (int u = 0; u < 8; ++u) acc[u] = fmaf(rlf(v[u], k), w, acc[u]);
    }
#pragma unroll
    for (int u = 0; u < 8; ++u) {
        v[u] = fmaxf(acc[u], 0.f);
        acc[u] = b2r;
    }
#pragma unroll 8
    for (int k = 0; k < 64; ++k) {
        float w = w2s[k * 64 + lane];
#pragma unroll
        for (int u = 0; u < 8; ++u) acc[u] = fmaf(rlf(v[u], k), w, acc[u]);
    }
#pragma unroll
    for (int u = 0; u < 8; ++u)
        h[(size_t)(n0 + u) * 64 + lane] = fmaxf(acc[u], 0.f);
}

// K4: pair decoder via split-bf16 MFMA. 16 pairs per wave-task.
// A = feat[16 x 256] built on the fly: for k-step s, ALL lanes are in one
// section (sec = s>>1, k-half = s&1), so lane (q=lane>>4, p=lane&15) needs
// only e1/e2[p][half*32 + q*8 .. +8) -- 32 floats preloaded per lane.
// B = dw1 pre-split to bf16 hi/lo in LDS, fragment-ordered (ds_read_b128).
// acc[t] += Ah*Bh + Al*Bh + Ah*Bl  (lo*lo dropped, rel ~2^-18).
__global__ void __launch_bounds__(1024) k4_pair(const float* __restrict__ h,
                        const int* __restrict__ qidx,
                        const float* __restrict__ dw1, const float* __restrict__ db1,
                        const float* __restrict__ dw2, const float* __restrict__ db2,
                        float* __restrict__ out, int numWaves) {
    __shared__ short8 BH[2048];   // [s(8)][t(4)][lane(64)] of 8 bf16 -> 32 KB
    __shared__ short8 BL[2048];   // lo part -> 32 KB (total 64 KB exactly)
    int tid = threadIdx.x;
    // Stage dw1: frag element (s,t,lane,j): K = s*32 + (lane>>4)*8 + j,
    // n = t*16 + (lane&15). B-frag layout: B[k=q*8+j][n=lane&15].
    for (int f = tid; f < 2048; f += 1024) {
        int lane = f & 63, st = f >> 6;
        int t = st & 3, s = st >> 2;
        int q = lane >> 4, nl = lane & 15;
        int n = t * 16 + nl;
        int K0 = s * 32 + q * 8;
        float w[8];
#pragma unroll
        for (int j = 0; j < 8; ++j) w[j] = dw1[(K0 + j) * 64 + n];
        short8 hi, lo;
        split8(w, hi, lo);
        BH[f] = hi;
        BL[f] = lo;
    }
    __syncthreads();
    int lane = tid & 63;
    int q = lane >> 4, nl = lane & 15;
    float db1t[4], dw2t[4];
#pragma unroll
    for (int t = 0; t < 4; ++t) {
        db1t[t] = db1[t * 16 + nl];
        dw2t[t] = dw2[t * 16 + nl];
    }
    float db2v = db2[0];
    int wid = (blockIdx.x * 1024 + tid) >> 6;
    for (int task = wid; task < NPAIRS / 16; task += numWaves) {
        int p0 = task * 16;
        int i1 = qidx[p0 + nl];
        int i2 = qidx[NPAIRS + p0 + nl];
        const float4* r1 = (const float4*)(h + (size_t)i1 * 64);
        const float4* r2 = (const float4*)(h + (size_t)i2 * 64);
        float4 a0 = r1[q * 2],     a1 = r1[q * 2 + 1];
        float4 b0 = r1[8 + q * 2], b1 = r1[8 + q * 2 + 1];
        float4 c0 = r2[q * 2],     c1 = r2[q * 2 + 1];
        float4 d0 = r2[8 + q * 2], d1 = r2[8 + q * 2 + 1];
        float e1a[8] = {a0.x, a0.y, a0.z, a0.w, a1.x, a1.y, a1.z, a1.w};
        float e1b[8] = {b0.x, b0.y, b0.z, b0.w, b1.x, b1.y, b1.z, b1.w};
        float e2a[8] = {c0.x, c0.y, c0.z, c0.w, c1.x, c1.y, c1.z, c1.w};
        float e2b[8] = {d0.x, d0.y, d0.z, d0.w, d1.x, d1.y, d1.z, d1.w};
        floatx4 acc[4];
#pragma unroll
        for (int t = 0; t < 4; ++t) acc[t] = (floatx4){0.f, 0.f, 0.f, 0.f};

#define DO_STEP(S, EXPR)                                                      \
        {                                                                     \
            float f8[8];                                                      \
            _Pragma("unroll")                                                 \
            for (int j = 0; j < 8; ++j) { f8[j] = (EXPR); }                   \
            short8 Ah, Al;                                                    \
            split8(f8, Ah, Al);                                               \
            _Pragma("unroll")                                                 \
            for (int t = 0; t < 4; ++t) {                                     \
                short8 bh = BH[((S) * 4 + t) * 64 + lane];                    \
                short8 bl = BL[((S) * 4 + t) * 64 + lane];                    \
                acc[t] = __builtin_amdgcn_mfma_f32_16x16x32_bf16(Ah, bh, acc[t], 0, 0, 0); \
                acc[t] = __builtin_amdgcn_mfma_f32_16x16x32_bf16(Al, bh, acc[t], 0, 0, 0); \
                acc[t] = __builtin_amdgcn_mfma_f32_16x16x32_bf16(Ah, bl, acc[t], 0, 0, 0); \
            }                                                                 \
        }

        DO_STEP(0, e1a[j] + e2a[j])   // section 0 (e1+e2), k 0..31
        DO_STEP(1, e1b[j] + e2b[j])   // section 0, k 32..63
        DO_STEP(2, e1a[j] * e2a[j])   // section 1 (e1*e2), k 0..31
        DO_STEP(3, e1b[j] * e2b[j])   // section 1, k 32..63
        DO_STEP(4, e1a[j])            // section 2 (e1)
        DO_STEP(5, e1b[j])
        DO_STEP(6, e2a[j])            // section 3 (e2)
        DO_STEP(7, e2b[j])
#undef DO_STEP

        // Epilogue: D[m = q*4+r][n = t*16+nl] in acc[t][r].
        // logit_m = sum_n relu(D + db1[n]) * dw2[n] + db2
        float part[4] = {0.f, 0.f, 0.f, 0.f};
#pragma unroll
        for (int t = 0; t < 4; ++t) {
#pragma unroll
            for (int r = 0; r < 4; ++r)
                part[r] = fmaf(fmaxf(acc[t][r] + db1t[t], 0.f), dw2t[t], part[r]);
        }
#pragma unroll
        for (int off = 1; off < 16; off <<= 1) {
#pragma unroll
            for (int r = 0; r < 4; ++r) part[r] += __shfl_xor(part[r], off, 64);
        }
        if (nl == 0) {
#pragma unroll
            for (int r = 0; r < 4; ++r) out[p0 + q * 4 + r] = part[r] + db2v;
        }
    }
}

extern "C" void kernel_launch(void* const* d_in, const int* in_sizes, int n_in,
                              void* d_out, int out_size, void* d_ws, size_t ws_size,
                              hipStream_t stream) {
    const float* x    = (const float*)d_in[0];   // [N,64]
    const int*   eidx = (const int*)d_in[1];     // [2,E]
    const int*   qidx = (const int*)d_in[3];     // [2,P]
    const float* w1   = (const float*)d_in[4];
    const float* b1   = (const float*)d_in[5];
    const float* w2   = (const float*)d_in[6];
    const float* b2   = (const float*)d_in[7];
    const float* dw1  = (const float*)d_in[8];   // [256,64]
    const float* db1  = (const float*)d_in[9];
    const float* dw2  = (const float*)d_in[10];  // [64]
    const float* db2  = (const float*)d_in[11];  // [1]
    float* out = (float*)d_out;                  // [P]

    char* ws = (char*)d_ws;
    float* h0    = (float*)ws;
    int*   deg   = (int*)(ws + (size_t)N_NODES * FDIM * 4);
    int*   slots = (int*)(ws + (size_t)N_NODES * FDIM * 4 + (size_t)N_NODES * 4);

    const int* src = eidx;
    const int* dst = eidx + N_EDGES;

    k0_init<<<6250, 256, 0, stream>>>((const float4*)x, (float4*)h0, deg);
    k1_fill<<<6250, 256, 0, stream>>>(src, dst, x, h0, deg, slots);
    // K2: thread per (node, chunk): N*16 = 1.6M threads = 6250 x 256
    k2_agg<<<6250, 256, 0, stream>>>((const float4*)x, (float4*)h0, deg, slots);
    // K3: 8 nodes/wave, 12500 wave-tasks, 3125 blocks x 4 waves
    k3_mlp<<<3125, 256, 0, stream>>>(h0, w1, b1, w2, b2);
    // K4: 512 blocks x 16 waves = 8192 wave-slots, grid-stride over 12500 tasks
    const int blocks4 = 512;
    k4_pair<<<blocks4, 1024, 0, stream>>>(h0, qidx, dw1, db1, dw2, db2, out,
                                          blocks4 * 16);
}

// Round 4
// 420.410 us; speedup vs baseline: 1.4639x; 1.4639x over previous
//
#include <hip/hip_runtime.h>
#include <hip/hip_bf16.h>
#include <cstdint>

#define N_NODES 100000
#define N_EDGES 1600000
#define FDIM 64
#define NPAIRS 200000
#define CAP 64

typedef __attribute__((ext_vector_type(8))) short short8;
typedef __attribute__((ext_vector_type(4))) float floatx4;

__device__ __forceinline__ float rlf(float v, int lane) {
    return __int_as_float(__builtin_amdgcn_readlane(__float_as_int(v), lane));
}

__device__ __forceinline__ unsigned short bf16_rtne(float f) {
    unsigned u = __float_as_uint(f);
    unsigned r = (u + 0x7fffu + ((u >> 16) & 1u)) >> 16;
    return (unsigned short)r;
}

// B-side split (staging, amortized): RTNE hi + RTNE lo, hi+lo ~ f to 2^-17.
__device__ __forceinline__ void split8_rtne(const float* f, short8& hi, short8& lo) {
#pragma unroll
    for (int j = 0; j < 8; ++j) {
        unsigned short h = bf16_rtne(f[j]);
        hi[j] = (short)h;
        float hf = __uint_as_float(((unsigned)h) << 16);
        lo[j] = (short)bf16_rtne(f[j] - hf);
    }
}

// A-side split (hot loop): truncation. hi = top 16 bits (residual captured
// EXACTLY by lo up to lo's own trunc ~2^-14 abs rel). ~4 VALU/elem vs ~10.
__device__ __forceinline__ void split8_trunc(const float* f, short8& hi, short8& lo) {
#pragma unroll
    for (int j = 0; j < 8; ++j) {
        unsigned u = __float_as_uint(f[j]);
        hi[j] = (short)(unsigned short)(u >> 16);
        float hf = __uint_as_float(u & 0xffff0000u);
        float r = f[j] - hf;
        lo[j] = (short)(unsigned short)(__float_as_uint(r) >> 16);
    }
}

// K0: h0 = 2*x (self term: (1+eps)*x + x inside agg), deg = 0
__global__ void k0_init(const float4* __restrict__ x4, float4* __restrict__ h04,
                        int* __restrict__ deg) {
    int i = blockIdx.x * blockDim.x + threadIdx.x;
    if (i < N_NODES * FDIM / 4) {
        float4 v = x4[i];
        v.x *= 2.f; v.y *= 2.f; v.z *= 2.f; v.w *= 2.f;
        h04[i] = v;
    }
    if (i < N_NODES) deg[i] = 0;
}

// K1: bucket edges by dst. Overflow (deg > CAP) falls back to direct atomics.
__global__ void k1_fill(const int* __restrict__ src, const int* __restrict__ dst,
                        const float* __restrict__ x, float* __restrict__ h0,
                        int* __restrict__ deg, int* __restrict__ slots) {
    int e = blockIdx.x * blockDim.x + threadIdx.x;
    if (e >= N_EDGES) return;
    int s = src[e], d = dst[e];
    int pos = atomicAdd(&deg[d], 1);
    if (pos < CAP) {
        slots[(size_t)d * CAP + pos] = s;
    } else {
        const float* xr = x + (size_t)s * FDIM;
        float* hr = h0 + (size_t)d * FDIM;
        for (int f = 0; f < FDIM; ++f) atomicAdd(&hr[f], xr[f]);
    }
}

// K2: thread per (node, float4-chunk): 16 threads/node, int4 slot loads
// (coalesce to one fetch per node-group), 4 gathers in flight.
__global__ void __launch_bounds__(256) k2_agg(const float4* __restrict__ x4,
                       float4* __restrict__ h04,
                       const int* __restrict__ deg, const int* __restrict__ slots) {
    int gid = blockIdx.x * 256 + threadIdx.x;   // 1.6M = N*16
    int n = gid >> 4, fq = gid & 15;
    int dc = deg[n];
    if (dc > CAP) dc = CAP;
    const int4* srow = (const int4*)(slots + (size_t)n * CAP);
    float4 acc = h04[(size_t)n * 16 + fq];      // 2x + overflow atomics
    for (int i = 0; i < dc; i += 4) {
        int4 s4 = srow[i >> 2];
        float4 v = x4[(size_t)s4.x * 16 + fq];
        acc.x += v.x; acc.y += v.y; acc.z += v.z; acc.w += v.w;
        if (i + 1 < dc) {
            float4 u = x4[(size_t)s4.y * 16 + fq];
            acc.x += u.x; acc.y += u.y; acc.z += u.z; acc.w += u.w;
        }
        if (i + 2 < dc) {
            float4 u = x4[(size_t)s4.z * 16 + fq];
            acc.x += u.x; acc.y += u.y; acc.z += u.z; acc.w += u.w;
        }
        if (i + 3 < dc) {
            float4 u = x4[(size_t)s4.w * 16 + fq];
            acc.x += u.x; acc.y += u.y; acc.z += u.z; acc.w += u.w;
        }
    }
    h04[(size_t)n * 16 + fq] = acc;
}

// K3: node MLP, in-place, 8 nodes per wave.
__global__ void __launch_bounds__(256) k3_mlp(float* __restrict__ h,
                       const float* __restrict__ w1, const float* __restrict__ b1,
                       const float* __restrict__ w2, const float* __restrict__ b2) {
    __shared__ float w1s[64 * 64];
    __shared__ float w2s[64 * 64];
    int tid = threadIdx.x;
    const float4* w14 = (const float4*)w1;
    const float4* w24 = (const float4*)w2;
    float4* w1s4 = (float4*)w1s;
    float4* w2s4 = (float4*)w2s;
    for (int i = tid; i < 64 * 64 / 4; i += 256) {
        w1s4[i] = w14[i];
        w2s4[i] = w24[i];
    }
    __syncthreads();
    int lane = tid & 63;
    int wid = blockIdx.x * 4 + (tid >> 6);
    int n0 = wid * 8;
    float b1r = b1[lane], b2r = b2[lane];
    float v[8], acc[8];
#pragma unroll
    for (int u = 0; u < 8; ++u) {
        v[u] = h[(size_t)(n0 + u) * 64 + lane];
        acc[u] = b1r;
    }
#pragma unroll 8
    for (int k = 0; k < 64; ++k) {
        float w = w1s[k * 64 + lane];
#pragma unroll
        for (int u = 0; u < 8; ++u) acc[u] = fmaf(rlf(v[u], k), w, acc[u]);
    }
#pragma unroll
    for (int u = 0; u < 8; ++u) {
        v[u] = fmaxf(acc[u], 0.f);
        acc[u] = b2r;
    }
#pragma unroll 8
    for (int k = 0; k < 64; ++k) {
        float w = w2s[k * 64 + lane];
#pragma unroll
        for (int u = 0; u < 8; ++u) acc[u] = fmaf(rlf(v[u], k), w, acc[u]);
    }
#pragma unroll
    for (int u = 0; u < 8; ++u)
        h[(size_t)(n0 + u) * 64 + lane] = fmaxf(acc[u], 0.f);
}

// K4: pair decoder via split-bf16 MFMA, 16 pairs/wave-task, 256-thread block
// (4 waves) so the register allocator is NOT capped -> no scratch spill
// (R3 failure: __launch_bounds__(1024) forced VGPR=64 -> 900 MB spill traffic).
__global__ void __launch_bounds__(256) k4_pair(const float* __restrict__ h,
                        const int* __restrict__ qidx,
                        const float* __restrict__ dw1, const float* __restrict__ db1,
                        const float* __restrict__ dw2, const float* __restrict__ db2,
                        float* __restrict__ out, int numWaves) {
    __shared__ short8 BH[2048];   // [s(8)][t(4)][lane(64)] -> 32 KB
    __shared__ short8 BL[2048];   // lo part -> 32 KB (total 64 KB)
    int tid = threadIdx.x;
    // Stage dw1 in B-fragment order: (s,t,lane,j): K = s*32+(lane>>4)*8+j,
    // n = t*16 + (lane&15).
    for (int f = tid; f < 2048; f += 256) {
        int lane = f & 63, st = f >> 6;
        int t = st & 3, s = st >> 2;
        int q = lane >> 4, nl = lane & 15;
        int n = t * 16 + nl;
        int K0 = s * 32 + q * 8;
        float w[8];
#pragma unroll
        for (int j = 0; j < 8; ++j) w[j] = dw1[(K0 + j) * 64 + n];
        short8 hi, lo;
        split8_rtne(w, hi, lo);
        BH[f] = hi;
        BL[f] = lo;
    }
    __syncthreads();
    int lane = tid & 63;
    int q = lane >> 4, nl = lane & 15;
    float db1t[4], dw2t[4];
#pragma unroll
    for (int t = 0; t < 4; ++t) {
        db1t[t] = db1[t * 16 + nl];
        dw2t[t] = dw2[t * 16 + nl];
    }
    float db2v = db2[0];
    int wid = (blockIdx.x * 256 + tid) >> 6;
    for (int task = wid; task < NPAIRS / 16; task += numWaves) {
        int p0 = task * 16;
        int i1 = qidx[p0 + nl];
        int i2 = qidx[NPAIRS + p0 + nl];
        const float4* r1 = (const float4*)(h + (size_t)i1 * 64);
        const float4* r2 = (const float4*)(h + (size_t)i2 * 64);
        float4 a0 = r1[q * 2],     a1 = r1[q * 2 + 1];
        float4 b0 = r1[8 + q * 2], b1 = r1[8 + q * 2 + 1];
        float4 c0 = r2[q * 2],     c1 = r2[q * 2 + 1];
        float4 d0 = r2[8 + q * 2], d1 = r2[8 + q * 2 + 1];
        float e1a[8] = {a0.x, a0.y, a0.z, a0.w, a1.x, a1.y, a1.z, a1.w};
        float e1b[8] = {b0.x, b0.y, b0.z, b0.w, b1.x, b1.y, b1.z, b1.w};
        float e2a[8] = {c0.x, c0.y, c0.z, c0.w, c1.x, c1.y, c1.z, c1.w};
        float e2b[8] = {d0.x, d0.y, d0.z, d0.w, d1.x, d1.y, d1.z, d1.w};
        floatx4 acc[4];
#pragma unroll
        for (int t = 0; t < 4; ++t) acc[t] = (floatx4){0.f, 0.f, 0.f, 0.f};

#define DO_STEP(S, EXPR)                                                      \
        {                                                                     \
            float f8[8];                                                      \
            _Pragma("unroll")                                                 \
            for (int j = 0; j < 8; ++j) { f8[j] = (EXPR); }                   \
            short8 Ah, Al;                                                    \
            split8_trunc(f8, Ah, Al);                                         \
            _Pragma("unroll")                                                 \
            for (int t = 0; t < 4; ++t) {                                     \
                short8 bh = BH[((S) * 4 + t) * 64 + lane];                    \
                short8 bl = BL[((S) * 4 + t) * 64 + lane];                    \
                acc[t] = __builtin_amdgcn_mfma_f32_16x16x32_bf16(Ah, bh, acc[t], 0, 0, 0); \
                acc[t] = __builtin_amdgcn_mfma_f32_16x16x32_bf16(Al, bh, acc[t], 0, 0, 0); \
                acc[t] = __builtin_amdgcn_mfma_f32_16x16x32_bf16(Ah, bl, acc[t], 0, 0, 0); \
            }                                                                 \
        }

        DO_STEP(0, e1a[j] + e2a[j])   // section 0 (e1+e2), k 0..31
        DO_STEP(1, e1b[j] + e2b[j])   // section 0, k 32..63
        DO_STEP(2, e1a[j] * e2a[j])   // section 1 (e1*e2), k 0..31
        DO_STEP(3, e1b[j] * e2b[j])   // section 1, k 32..63
        DO_STEP(4, e1a[j])            // section 2 (e1)
        DO_STEP(5, e1b[j])
        DO_STEP(6, e2a[j])            // section 3 (e2)
        DO_STEP(7, e2b[j])
#undef DO_STEP

        // D[m = q*4+r][n = t*16+nl] in acc[t][r].
        float part[4] = {0.f, 0.f, 0.f, 0.f};
#pragma unroll
        for (int t = 0; t < 4; ++t) {
#pragma unroll
            for (int r = 0; r < 4; ++r)
                part[r] = fmaf(fmaxf(acc[t][r] + db1t[t], 0.f), dw2t[t], part[r]);
        }
#pragma unroll
        for (int off = 1; off < 16; off <<= 1) {
#pragma unroll
            for (int r = 0; r < 4; ++r) part[r] += __shfl_xor(part[r], off, 64);
        }
        if (nl == 0) {
#pragma unroll
            for (int r = 0; r < 4; ++r) out[p0 + q * 4 + r] = part[r] + db2v;
        }
    }
}

extern "C" void kernel_launch(void* const* d_in, const int* in_sizes, int n_in,
                              void* d_out, int out_size, void* d_ws, size_t ws_size,
                              hipStream_t stream) {
    const float* x    = (const float*)d_in[0];   // [N,64]
    const int*   eidx = (const int*)d_in[1];     // [2,E]
    const int*   qidx = (const int*)d_in[3];     // [2,P]
    const float* w1   = (const float*)d_in[4];
    const float* b1   = (const float*)d_in[5];
    const float* w2   = (const float*)d_in[6];
    const float* b2   = (const float*)d_in[7];
    const float* dw1  = (const float*)d_in[8];   // [256,64]
    const float* db1  = (const float*)d_in[9];
    const float* dw2  = (const float*)d_in[10];  // [64]
    const float* db2  = (const float*)d_in[11];  // [1]
    float* out = (float*)d_out;                  // [P]

    char* ws = (char*)d_ws;
    float* h0    = (float*)ws;
    int*   deg   = (int*)(ws + (size_t)N_NODES * FDIM * 4);
    int*   slots = (int*)(ws + (size_t)N_NODES * FDIM * 4 + (size_t)N_NODES * 4);

    const int* src = eidx;
    const int* dst = eidx + N_EDGES;

    k0_init<<<6250, 256, 0, stream>>>((const float4*)x, (float4*)h0, deg);
    k1_fill<<<6250, 256, 0, stream>>>(src, dst, x, h0, deg, slots);
    // K2: thread per (node, chunk): N*16 = 1.6M threads
    k2_agg<<<6250, 256, 0, stream>>>((const float4*)x, (float4*)h0, deg, slots);
    // K3: 8 nodes/wave, 12500 wave-tasks
    k3_mlp<<<3125, 256, 0, stream>>>(h0, w1, b1, w2, b2);
    // K4: 625 blocks x 4 waves = 2500 waves -> exactly 5 tasks/wave
    const int blocks4 = 625;
    k4_pair<<<blocks4, 256, 0, stream>>>(h0, qidx, dw1, db1, dw2, db2, out,
                                         blocks4 * 4);
}

// Round 5
// 414.515 us; speedup vs baseline: 1.4847x; 1.0142x over previous
//
#include <hip/hip_runtime.h>
#include <hip/hip_bf16.h>
#include <cstdint>

#define N_NODES 100000
#define N_EDGES 1600000
#define FDIM 64
#define NPAIRS 200000
#define CAP 48          // slots per node; overflow falls back to atomics

typedef __attribute__((ext_vector_type(8))) short short8;
typedef __attribute__((ext_vector_type(4))) float floatx4;

__device__ __forceinline__ float rlf(float v, int lane) {
    return __int_as_float(__builtin_amdgcn_readlane(__float_as_int(v), lane));
}

__device__ __forceinline__ unsigned short bf16_rtne(float f) {
    unsigned u = __float_as_uint(f);
    unsigned r = (u + 0x7fffu + ((u >> 16) & 1u)) >> 16;
    return (unsigned short)r;
}

// B-side split (staging, amortized): RTNE hi + RTNE lo.
__device__ __forceinline__ void split8_rtne(const float* f, short8& hi, short8& lo) {
#pragma unroll
    for (int j = 0; j < 8; ++j) {
        unsigned short h = bf16_rtne(f[j]);
        hi[j] = (short)h;
        float hf = __uint_as_float(((unsigned)h) << 16);
        lo[j] = (short)bf16_rtne(f[j] - hf);
    }
}

// A-side split (hot loop): truncation, ~4 VALU/elem.
__device__ __forceinline__ void split8_trunc(const float* f, short8& hi, short8& lo) {
#pragma unroll
    for (int j = 0; j < 8; ++j) {
        unsigned u = __float_as_uint(f[j]);
        hi[j] = (short)(unsigned short)(u >> 16);
        float hf = __uint_as_float(u & 0xffff0000u);
        float r = f[j] - hf;
        lo[j] = (short)(unsigned short)(__float_as_uint(r) >> 16);
    }
}

// K0: h0 = 2*x; zero the padded degree counters (one per 64B line).
__global__ void k0_init(const float4* __restrict__ x4, float4* __restrict__ h04,
                        int* __restrict__ deg_pad) {
    int i = blockIdx.x * blockDim.x + threadIdx.x;
    if (i < N_NODES * FDIM / 4) {
        float4 v = x4[i];
        v.x *= 2.f; v.y *= 2.f; v.z *= 2.f; v.w *= 2.f;
        h04[i] = v;
    }
    if (i < N_NODES) deg_pad[i * 16] = 0;
}

// K1: bucket edges by dst. Degree counter padded to its own cache line
// (R4 diagnosis: 16 counters/line x 16 RMW each = 256 contended RMWs per
// line bouncing across XCDs = 88 ns/atomic). Overflow (pos >= CAP) falls
// back to direct f32 atomics into h0 -- correct for any degree distribution.
__global__ void k1_fill(const int* __restrict__ src, const int* __restrict__ dst,
                        const float* __restrict__ x, float* __restrict__ h0,
                        int* __restrict__ deg_pad, int* __restrict__ slots) {
    int e = blockIdx.x * blockDim.x + threadIdx.x;
    if (e >= N_EDGES) return;
    int s = src[e], d = dst[e];
    int pos = atomicAdd(&deg_pad[d * 16], 1);
    if (pos < CAP) {
        slots[(size_t)d * CAP + pos] = s;
    } else {
        const float* xr = x + (size_t)s * FDIM;
        float* hr = h0 + (size_t)d * FDIM;
        for (int f = 0; f < FDIM; ++f) atomicAdd(&hr[f], xr[f]);
    }
}

// K2: thread per (node, float4-chunk): 16 threads/node; int4 slot loads;
// 8 row-gathers in flight per iteration.
__global__ void __launch_bounds__(256) k2_agg(const float4* __restrict__ x4,
                       float4* __restrict__ h04,
                       const int* __restrict__ deg_pad, const int* __restrict__ slots) {
    int gid = blockIdx.x * 256 + threadIdx.x;   // 1.6M = N*16
    int n = gid >> 4, fq = gid & 15;
    int dc = deg_pad[n * 16];
    if (dc > CAP) dc = CAP;
    const int4* srow = (const int4*)(slots + (size_t)n * CAP);
    float4 acc = h04[(size_t)n * 16 + fq];      // 2x + overflow atomics
    for (int i = 0; i < dc; i += 8) {
        int4 s4 = srow[i >> 2];
        int4 s5;
        if (i + 4 < dc) s5 = srow[(i >> 2) + 1];
        float4 v0 = x4[(size_t)s4.x * 16 + fq];
        acc.x += v0.x; acc.y += v0.y; acc.z += v0.z; acc.w += v0.w;
        if (i + 1 < dc) {
            float4 u = x4[(size_t)s4.y * 16 + fq];
            acc.x += u.x; acc.y += u.y; acc.z += u.z; acc.w += u.w;
        }
        if (i + 2 < dc) {
            float4 u = x4[(size_t)s4.z * 16 + fq];
            acc.x += u.x; acc.y += u.y; acc.z += u.z; acc.w += u.w;
        }
        if (i + 3 < dc) {
            float4 u = x4[(size_t)s4.w * 16 + fq];
            acc.x += u.x; acc.y += u.y; acc.z += u.z; acc.w += u.w;
        }
        if (i + 4 < dc) {
            float4 u = x4[(size_t)s5.x * 16 + fq];
            acc.x += u.x; acc.y += u.y; acc.z += u.z; acc.w += u.w;
        }
        if (i + 5 < dc) {
            float4 u = x4[(size_t)s5.y * 16 + fq];
            acc.x += u.x; acc.y += u.y; acc.z += u.z; acc.w += u.w;
        }
        if (i + 6 < dc) {
            float4 u = x4[(size_t)s5.z * 16 + fq];
            acc.x += u.x; acc.y += u.y; acc.z += u.z; acc.w += u.w;
        }
        if (i + 7 < dc) {
            float4 u = x4[(size_t)s5.w * 16 + fq];
            acc.x += u.x; acc.y += u.y; acc.z += u.z; acc.w += u.w;
        }
    }
    h04[(size_t)n * 16 + fq] = acc;
}

// K3: node MLP, in-place, 8 nodes per wave.
__global__ void __launch_bounds__(256) k3_mlp(float* __restrict__ h,
                       const float* __restrict__ w1, const float* __restrict__ b1,
                       const float* __restrict__ w2, const float* __restrict__ b2) {
    __shared__ float w1s[64 * 64];
    __shared__ float w2s[64 * 64];
    int tid = threadIdx.x;
    const float4* w14 = (const float4*)w1;
    const float4* w24 = (const float4*)w2;
    float4* w1s4 = (float4*)w1s;
    float4* w2s4 = (float4*)w2s;
    for (int i = tid; i < 64 * 64 / 4; i += 256) {
        w1s4[i] = w14[i];
        w2s4[i] = w24[i];
    }
    __syncthreads();
    int lane = tid & 63;
    int wid = blockIdx.x * 4 + (tid >> 6);
    int n0 = wid * 8;
    float b1r = b1[lane], b2r = b2[lane];
    float v[8], acc[8];
#pragma unroll
    for (int u = 0; u < 8; ++u) {
        v[u] = h[(size_t)(n0 + u) * 64 + lane];
        acc[u] = b1r;
    }
#pragma unroll 8
    for (int k = 0; k < 64; ++k) {
        float w = w1s[k * 64 + lane];
#pragma unroll
        for (int u = 0; u < 8; ++u) acc[u] = fmaf(rlf(v[u], k), w, acc[u]);
    }
#pragma unroll
    for (int u = 0; u < 8; ++u) {
        v[u] = fmaxf(acc[u], 0.f);
        acc[u] = b2r;
    }
#pragma unroll 8
    for (int k = 0; k < 64; ++k) {
        float w = w2s[k * 64 + lane];
#pragma unroll
        for (int u = 0; u < 8; ++u) acc[u] = fmaf(rlf(v[u], k), w, acc[u]);
    }
#pragma unroll
    for (int u = 0; u < 8; ++u)
        h[(size_t)(n0 + u) * 64 + lane] = fmaxf(acc[u], 0.f);
}

// K4: pair decoder via split-bf16 MFMA, 16 pairs/wave-task, 256-thread block.
__global__ void __launch_bounds__(256) k4_pair(const float* __restrict__ h,
                        const int* __restrict__ qidx,
                        const float* __restrict__ dw1, const float* __restrict__ db1,
                        const float* __restrict__ dw2, const float* __restrict__ db2,
                        float* __restrict__ out, int numWaves) {
    __shared__ short8 BH[2048];   // [s(8)][t(4)][lane(64)] -> 32 KB
    __shared__ short8 BL[2048];   // lo part -> 32 KB (total 64 KB)
    int tid = threadIdx.x;
    for (int f = tid; f < 2048; f += 256) {
        int lane = f & 63, st = f >> 6;
        int t = st & 3, s = st >> 2;
        int q = lane >> 4, nl = lane & 15;
        int n = t * 16 + nl;
        int K0 = s * 32 + q * 8;
        float w[8];
#pragma unroll
        for (int j = 0; j < 8; ++j) w[j] = dw1[(K0 + j) * 64 + n];
        short8 hi, lo;
        split8_rtne(w, hi, lo);
        BH[f] = hi;
        BL[f] = lo;
    }
    __syncthreads();
    int lane = tid & 63;
    int q = lane >> 4, nl = lane & 15;
    float db1t[4], dw2t[4];
#pragma unroll
    for (int t = 0; t < 4; ++t) {
        db1t[t] = db1[t * 16 + nl];
        dw2t[t] = dw2[t * 16 + nl];
    }
    float db2v = db2[0];
    int wid = (blockIdx.x * 256 + tid) >> 6;
    for (int task = wid; task < NPAIRS / 16; task += numWaves) {
        int p0 = task * 16;
        int i1 = qidx[p0 + nl];
        int i2 = qidx[NPAIRS + p0 + nl];
        const float4* r1 = (const float4*)(h + (size_t)i1 * 64);
        const float4* r2 = (const float4*)(h + (size_t)i2 * 64);
        float4 a0 = r1[q * 2],     a1 = r1[q * 2 + 1];
        float4 b0 = r1[8 + q * 2], b1 = r1[8 + q * 2 + 1];
        float4 c0 = r2[q * 2],     c1 = r2[q * 2 + 1];
        float4 d0 = r2[8 + q * 2], d1 = r2[8 + q * 2 + 1];
        float e1a[8] = {a0.x, a0.y, a0.z, a0.w, a1.x, a1.y, a1.z, a1.w};
        float e1b[8] = {b0.x, b0.y, b0.z, b0.w, b1.x, b1.y, b1.z, b1.w};
        float e2a[8] = {c0.x, c0.y, c0.z, c0.w, c1.x, c1.y, c1.z, c1.w};
        float e2b[8] = {d0.x, d0.y, d0.z, d0.w, d1.x, d1.y, d1.z, d1.w};
        floatx4 acc[4];
#pragma unroll
        for (int t = 0; t < 4; ++t) acc[t] = (floatx4){0.f, 0.f, 0.f, 0.f};

#define DO_STEP(S, EXPR)                                                      \
        {                                                                     \
            float f8[8];                                                      \
            _Pragma("unroll")                                                 \
            for (int j = 0; j < 8; ++j) { f8[j] = (EXPR); }                   \
            short8 Ah, Al;                                                    \
            split8_trunc(f8, Ah, Al);                                         \
            _Pragma("unroll")                                                 \
            for (int t = 0; t < 4; ++t) {                                     \
                short8 bh = BH[((S) * 4 + t) * 64 + lane];                    \
                short8 bl = BL[((S) * 4 + t) * 64 + lane];                    \
                acc[t] = __builtin_amdgcn_mfma_f32_16x16x32_bf16(Ah, bh, acc[t], 0, 0, 0); \
                acc[t] = __builtin_amdgcn_mfma_f32_16x16x32_bf16(Al, bh, acc[t], 0, 0, 0); \
                acc[t] = __builtin_amdgcn_mfma_f32_16x16x32_bf16(Ah, bl, acc[t], 0, 0, 0); \
            }                                                                 \
        }

        DO_STEP(0, e1a[j] + e2a[j])
        DO_STEP(1, e1b[j] + e2b[j])
        DO_STEP(2, e1a[j] * e2a[j])
        DO_STEP(3, e1b[j] * e2b[j])
        DO_STEP(4, e1a[j])
        DO_STEP(5, e1b[j])
        DO_STEP(6, e2a[j])
        DO_STEP(7, e2b[j])
#undef DO_STEP

        float part[4] = {0.f, 0.f, 0.f, 0.f};
#pragma unroll
        for (int t = 0; t < 4; ++t) {
#pragma unroll
            for (int r = 0; r < 4; ++r)
                part[r] = fmaf(fmaxf(acc[t][r] + db1t[t], 0.f), dw2t[t], part[r]);
        }
#pragma unroll
        for (int off = 1; off < 16; off <<= 1) {
#pragma unroll
            for (int r = 0; r < 4; ++r) part[r] += __shfl_xor(part[r], off, 64);
        }
        if (nl == 0) {
#pragma unroll
            for (int r = 0; r < 4; ++r) out[p0 + q * 4 + r] = part[r] + db2v;
        }
    }
}

extern "C" void kernel_launch(void* const* d_in, const int* in_sizes, int n_in,
                              void* d_out, int out_size, void* d_ws, size_t ws_size,
                              hipStream_t stream) {
    const float* x    = (const float*)d_in[0];   // [N,64]
    const int*   eidx = (const int*)d_in[1];     // [2,E]
    const int*   qidx = (const int*)d_in[3];     // [2,P]
    const float* w1   = (const float*)d_in[4];
    const float* b1   = (const float*)d_in[5];
    const float* w2   = (const float*)d_in[6];
    const float* b2   = (const float*)d_in[7];
    const float* dw1  = (const float*)d_in[8];   // [256,64]
    const float* db1  = (const float*)d_in[9];
    const float* dw2  = (const float*)d_in[10];  // [64]
    const float* db2  = (const float*)d_in[11];  // [1]
    float* out = (float*)d_out;                  // [P]

    // ws layout (51.2 MB total, <= proven-safe 51.6 MB):
    //   h0      : N*64 f32 = 25.6 MB
    //   deg_pad : N*16 i32 =  6.4 MB  (counter at stride 16 -> own 64B line)
    //   slots   : N*48 i32 = 19.2 MB
    char* ws = (char*)d_ws;
    float* h0      = (float*)ws;
    int*   deg_pad = (int*)(ws + (size_t)N_NODES * FDIM * 4);
    int*   slots   = (int*)(ws + (size_t)N_NODES * FDIM * 4 + (size_t)N_NODES * 64);

    const int* src = eidx;
    const int* dst = eidx + N_EDGES;

    k0_init<<<6250, 256, 0, stream>>>((const float4*)x, (float4*)h0, deg_pad);
    k1_fill<<<6250, 256, 0, stream>>>(src, dst, x, h0, deg_pad, slots);
    k2_agg<<<6250, 256, 0, stream>>>((const float4*)x, (float4*)h0, deg_pad, slots);
    k3_mlp<<<3125, 256, 0, stream>>>(h0, w1, b1, w2, b2);
    const int blocks4 = 625;
    k4_pair<<<blocks4, 256, 0, stream>>>(h0, qidx, dw1, db1, dw2, db2, out,
                                         blocks4 * 4);
}

// Round 6
// 336.605 us; speedup vs baseline: 1.8284x; 1.2315x over previous
//
#include <hip/hip_runtime.h>
#include <hip/hip_bf16.h>
#include <cstdint>

#define N_NODES 100000
#define N_EDGES 1600000
#define FDIM 64
#define NPAIRS 200000
#define NB 391          // dst buckets: ceil(100000/256)
#define BCAP 6144       // bucket entry capacity (avg 4092, ~32 sigma slack)
#define CCAP 7168       // per-bucket CSR region (padded rows fit: 6144+768)
#define EPB 6250        // edges per block in p1 passes (256 blocks)

typedef __attribute__((ext_vector_type(8))) short short8;
typedef __attribute__((ext_vector_type(4))) float floatx4;

__device__ __forceinline__ float rlf(float v, int lane) {
    return __int_as_float(__builtin_amdgcn_readlane(__float_as_int(v), lane));
}

__device__ __forceinline__ unsigned short bf16_rtne(float f) {
    unsigned u = __float_as_uint(f);
    unsigned r = (u + 0x7fffu + ((u >> 16) & 1u)) >> 16;
    return (unsigned short)r;
}

__device__ __forceinline__ void split8_rtne(const float* f, short8& hi, short8& lo) {
#pragma unroll
    for (int j = 0; j < 8; ++j) {
        unsigned short h = bf16_rtne(f[j]);
        hi[j] = (short)h;
        float hf = __uint_as_float(((unsigned)h) << 16);
        lo[j] = (short)bf16_rtne(f[j] - hf);
    }
}

__device__ __forceinline__ void split8_trunc(const float* f, short8& hi, short8& lo) {
#pragma unroll
    for (int j = 0; j < 8; ++j) {
        unsigned u = __float_as_uint(f[j]);
        hi[j] = (short)(unsigned short)(u >> 16);
        float hf = __uint_as_float(u & 0xffff0000u);
        float r = f[j] - hf;
        lo[j] = (short)(unsigned short)(__float_as_uint(r) >> 16);
    }
}

// K0: h0 = 2*x (self term of GIN with self-loop)
__global__ void k0_init(const float4* __restrict__ x4, float4* __restrict__ h04) {
    int i = blockIdx.x * blockDim.x + threadIdx.x;
    if (i < N_NODES * FDIM / 4) {
        float4 v = x4[i];
        v.x *= 2.f; v.y *= 2.f; v.z *= 2.f; v.w *= 2.f;
        h04[i] = v;
    }
}

// P1a: per-block LDS histogram of dst buckets -> matrix[block][bucket]
__global__ void __launch_bounds__(256) p1a_hist(const int* __restrict__ dst,
                                                int* __restrict__ matrix) {
    __shared__ int hist[NB];
    int tid = threadIdx.x, blk = blockIdx.x;
    for (int i = tid; i < NB; i += 256) hist[i] = 0;
    __syncthreads();
    int base = blk * EPB;
    for (int i = tid; i < EPB; i += 256) {
        int d = dst[base + i];
        atomicAdd(&hist[d >> 8], 1);
    }
    __syncthreads();
    for (int i = tid; i < NB; i += 256) matrix[blk * NB + i] = hist[i];
}

// P1b: per-bucket exclusive scan over 256 block counts (in-place) + totals.
__global__ void __launch_bounds__(256) p1b_scan(int* __restrict__ matrix,
                                                int* __restrict__ bucketCnt) {
    __shared__ int s[256];
    int b = blockIdx.x, t = threadIdx.x;
    int v = matrix[t * NB + b];
    s[t] = v;
    __syncthreads();
    for (int off = 1; off < 256; off <<= 1) {
        int u = (t >= off) ? s[t - off] : 0;
        __syncthreads();
        s[t] += u;
        __syncthreads();
    }
    matrix[t * NB + b] = s[t] - v;           // exclusive prefix
    if (t == 255) bucketCnt[b] = s[255];
}

// P1c: scatter packed (dlow<<17 | src) into bucket arrays. LDS cursors only;
// per-(block,bucket) ranges are disjoint by construction -> no global atomics.
// Overflow beyond BCAP (adversarial only) falls back to correct h0 atomics.
__global__ void __launch_bounds__(256) p1c_scatter(const int* __restrict__ src,
        const int* __restrict__ dst, const float* __restrict__ x,
        float* __restrict__ h0, const int* __restrict__ matrix,
        int* __restrict__ bucketArr) {
    __shared__ int cur[NB];
    int tid = threadIdx.x, blk = blockIdx.x;
    for (int i = tid; i < NB; i += 256) cur[i] = matrix[blk * NB + i];
    __syncthreads();
    int base = blk * EPB;
    for (int i = tid; i < EPB; i += 256) {
        int e = base + i;
        int s = src[e], d = dst[e];
        int b = d >> 8;
        int pos = atomicAdd(&cur[b], 1);
        if (pos < BCAP) {
            bucketArr[b * BCAP + pos] = ((d & 255) << 17) | s;
        } else {
            const float* xr = x + (size_t)s * FDIM;
            float* hr = h0 + (size_t)d * FDIM;
            for (int f = 0; f < FDIM; ++f) atomicAdd(&hr[f], xr[f]);
        }
    }
}

// P2: per-bucket fine counting sort -> dense CSR (rows padded to 4 ints for
// aligned int4 consumption in k2) + rowptr + deg. LDS atomics only.
__global__ void __launch_bounds__(256) p2_build(const int* __restrict__ bucketArr,
        const int* __restrict__ bucketCnt, int* __restrict__ csr,
        int* __restrict__ rowptr, int* __restrict__ deg) {
    __shared__ int hist[256], sc[256], cur[256];
    int b = blockIdx.x, t = threadIdx.x;
    int cnt = bucketCnt[b];
    if (cnt > BCAP) cnt = BCAP;
    hist[t] = 0;
    __syncthreads();
    const int* arr = bucketArr + b * BCAP;
    for (int i = t; i < cnt; i += 256) atomicAdd(&hist[(arr[i] >> 17) & 255], 1);
    __syncthreads();
    int h = hist[t];
    int pc = (h + 3) & ~3;                   // pad row to 4 ints
    sc[t] = pc;
    __syncthreads();
    for (int off = 1; off < 256; off <<= 1) {
        int u = (t >= off) ? sc[t - off] : 0;
        __syncthreads();
        sc[t] += u;
        __syncthreads();
    }
    int rbase = sc[t] - pc;                  // exclusive padded prefix
    cur[t] = rbase;
    int n = (b << 8) + t;
    if (n < N_NODES) {
        rowptr[n] = b * CCAP + rbase;
        deg[n] = h;
    }
    __syncthreads();
    for (int i = t; i < cnt; i += 256) {
        int e = arr[i];
        int dl = (e >> 17) & 255;
        int s = e & 0x1FFFF;
        int pos = atomicAdd(&cur[dl], 1);
        csr[b * CCAP + pos] = s;
    }
}

// K2: thread per (node, float4-chunk): 16 threads/node; dense CSR; guarded
// int4 loads (rows 16B-aligned via padding); 8 row-gathers in flight.
__global__ void __launch_bounds__(256) k2_agg(const float4* __restrict__ x4,
                       float4* __restrict__ h04, const int* __restrict__ deg,
                       const int* __restrict__ rowptr, const int* __restrict__ csr) {
    int gid = blockIdx.x * 256 + threadIdx.x;   // 1.6M = N*16
    int n = gid >> 4, fq = gid & 15;
    int dc = deg[n];
    const int4* srow = (const int4*)(csr + rowptr[n]);
    float4 acc = h04[(size_t)n * 16 + fq];      // 2x + overflow atomics
    for (int i = 0; i < dc; i += 8) {
        int4 s4 = srow[i >> 2];
        int4 s5;
        if (i + 4 < dc) s5 = srow[(i >> 2) + 1];
        float4 v0 = x4[(size_t)s4.x * 16 + fq];
        acc.x += v0.x; acc.y += v0.y; acc.z += v0.z; acc.w += v0.w;
        if (i + 1 < dc) {
            float4 u = x4[(size_t)s4.y * 16 + fq];
            acc.x += u.x; acc.y += u.y; acc.z += u.z; acc.w += u.w;
        }
        if (i + 2 < dc) {
            float4 u = x4[(size_t)s4.z * 16 + fq];
            acc.x += u.x; acc.y += u.y; acc.z += u.z; acc.w += u.w;
        }
        if (i + 3 < dc) {
            float4 u = x4[(size_t)s4.w * 16 + fq];
            acc.x += u.x; acc.y += u.y; acc.z += u.z; acc.w += u.w;
        }
        if (i + 4 < dc) {
            float4 u = x4[(size_t)s5.x * 16 + fq];
            acc.x += u.x; acc.y += u.y; acc.z += u.z; acc.w += u.w;
        }
        if (i + 5 < dc) {
            float4 u = x4[(size_t)s5.y * 16 + fq];
            acc.x += u.x; acc.y += u.y; acc.z += u.z; acc.w += u.w;
        }
        if (i + 6 < dc) {
            float4 u = x4[(size_t)s5.z * 16 + fq];
            acc.x += u.x; acc.y += u.y; acc.z += u.z; acc.w += u.w;
        }
        if (i + 7 < dc) {
            float4 u = x4[(size_t)s5.w * 16 + fq];
            acc.x += u.x; acc.y += u.y; acc.z += u.z; acc.w += u.w;
        }
    }
    h04[(size_t)n * 16 + fq] = acc;
}

// K3: node MLP, in-place, 8 nodes per wave.
__global__ void __launch_bounds__(256) k3_mlp(float* __restrict__ h,
                       const float* __restrict__ w1, const float* __restrict__ b1,
                       const float* __restrict__ w2, const float* __restrict__ b2) {
    __shared__ float w1s[64 * 64];
    __shared__ float w2s[64 * 64];
    int tid = threadIdx.x;
    const float4* w14 = (const float4*)w1;
    const float4* w24 = (const float4*)w2;
    float4* w1s4 = (float4*)w1s;
    float4* w2s4 = (float4*)w2s;
    for (int i = tid; i < 64 * 64 / 4; i += 256) {
        w1s4[i] = w14[i];
        w2s4[i] = w24[i];
    }
    __syncthreads();
    int lane = tid & 63;
    int wid = blockIdx.x * 4 + (tid >> 6);
    int n0 = wid * 8;
    float b1r = b1[lane], b2r = b2[lane];
    float v[8], acc[8];
#pragma unroll
    for (int u = 0; u < 8; ++u) {
        v[u] = h[(size_t)(n0 + u) * 64 + lane];
        acc[u] = b1r;
    }
#pragma unroll 8
    for (int k = 0; k < 64; ++k) {
        float w = w1s[k * 64 + lane];
#pragma unroll
        for (int u = 0; u < 8; ++u) acc[u] = fmaf(rlf(v[u], k), w, acc[u]);
    }
#pragma unroll
    for (int u = 0; u < 8; ++u) {
        v[u] = fmaxf(acc[u], 0.f);
        acc[u] = b2r;
    }
#pragma unroll 8
    for (int k = 0; k < 64; ++k) {
        float w = w2s[k * 64 + lane];
#pragma unroll
        for (int u = 0; u < 8; ++u) acc[u] = fmaf(rlf(v[u], k), w, acc[u]);
    }
#pragma unroll
    for (int u = 0; u < 8; ++u)
        h[(size_t)(n0 + u) * 64 + lane] = fmaxf(acc[u], 0.f);
}

// K4: pair decoder via split-bf16 MFMA, 16 pairs/wave-task, 256-thread block.
__global__ void __launch_bounds__(256) k4_pair(const float* __restrict__ h,
                        const int* __restrict__ qidx,
                        const float* __restrict__ dw1, const float* __restrict__ db1,
                        const float* __restrict__ dw2, const float* __restrict__ db2,
                        float* __restrict__ out, int numWaves) {
    __shared__ short8 BH[2048];
    __shared__ short8 BL[2048];
    int tid = threadIdx.x;
    for (int f = tid; f < 2048; f += 256) {
        int lane = f & 63, st = f >> 6;
        int t = st & 3, s = st >> 2;
        int q = lane >> 4, nl = lane & 15;
        int n = t * 16 + nl;
        int K0 = s * 32 + q * 8;
        float w[8];
#pragma unroll
        for (int j = 0; j < 8; ++j) w[j] = dw1[(K0 + j) * 64 + n];
        short8 hi, lo;
        split8_rtne(w, hi, lo);
        BH[f] = hi;
        BL[f] = lo;
    }
    __syncthreads();
    int lane = tid & 63;
    int q = lane >> 4, nl = lane & 15;
    float db1t[4], dw2t[4];
#pragma unroll
    for (int t = 0; t < 4; ++t) {
        db1t[t] = db1[t * 16 + nl];
        dw2t[t] = dw2[t * 16 + nl];
    }
    float db2v = db2[0];
    int wid = (blockIdx.x * 256 + tid) >> 6;
    for (int task = wid; task < NPAIRS / 16; task += numWaves) {
        int p0 = task * 16;
        int i1 = qidx[p0 + nl];
        int i2 = qidx[NPAIRS + p0 + nl];
        const float4* r1 = (const float4*)(h + (size_t)i1 * 64);
        const float4* r2 = (const float4*)(h + (size_t)i2 * 64);
        float4 a0 = r1[q * 2],     a1 = r1[q * 2 + 1];
        float4 b0 = r1[8 + q * 2], b1 = r1[8 + q * 2 + 1];
        float4 c0 = r2[q * 2],     c1 = r2[q * 2 + 1];
        float4 d0 = r2[8 + q * 2], d1 = r2[8 + q * 2 + 1];
        float e1a[8] = {a0.x, a0.y, a0.z, a0.w, a1.x, a1.y, a1.z, a1.w};
        float e1b[8] = {b0.x, b0.y, b0.z, b0.w, b1.x, b1.y, b1.z, b1.w};
        float e2a[8] = {c0.x, c0.y, c0.z, c0.w, c1.x, c1.y, c1.z, c1.w};
        float e2b[8] = {d0.x, d0.y, d0.z, d0.w, d1.x, d1.y, d1.z, d1.w};
        floatx4 acc[4];
#pragma unroll
        for (int t = 0; t < 4; ++t) acc[t] = (floatx4){0.f, 0.f, 0.f, 0.f};

#define DO_STEP(S, EXPR)                                                      \
        {                                                                     \
            float f8[8];                                                      \
            _Pragma("unroll")                                                 \
            for (int j = 0; j < 8; ++j) { f8[j] = (EXPR); }                   \
            short8 Ah, Al;                                                    \
            split8_trunc(f8, Ah, Al);                                         \
            _Pragma("unroll")                                                 \
            for (int t = 0; t < 4; ++t) {                                     \
                short8 bh = BH[((S) * 4 + t) * 64 + lane];                    \
                short8 bl = BL[((S) * 4 + t) * 64 + lane];                    \
                acc[t] = __builtin_amdgcn_mfma_f32_16x16x32_bf16(Ah, bh, acc[t], 0, 0, 0); \
                acc[t] = __builtin_amdgcn_mfma_f32_16x16x32_bf16(Al, bh, acc[t], 0, 0, 0); \
                acc[t] = __builtin_amdgcn_mfma_f32_16x16x32_bf16(Ah, bl, acc[t], 0, 0, 0); \
            }                                                                 \
        }

        DO_STEP(0, e1a[j] + e2a[j])
        DO_STEP(1, e1b[j] + e2b[j])
        DO_STEP(2, e1a[j] * e2a[j])
        DO_STEP(3, e1b[j] * e2b[j])
        DO_STEP(4, e1a[j])
        DO_STEP(5, e1b[j])
        DO_STEP(6, e2a[j])
        DO_STEP(7, e2b[j])
#undef DO_STEP

        float part[4] = {0.f, 0.f, 0.f, 0.f};
#pragma unroll
        for (int t = 0; t < 4; ++t) {
#pragma unroll
            for (int r = 0; r < 4; ++r)
                part[r] = fmaf(fmaxf(acc[t][r] + db1t[t], 0.f), dw2t[t], part[r]);
        }
#pragma unroll
        for (int off = 1; off < 16; off <<= 1) {
#pragma unroll
            for (int r = 0; r < 4; ++r) part[r] += __shfl_xor(part[r], off, 64);
        }
        if (nl == 0) {
#pragma unroll
            for (int r = 0; r < 4; ++r) out[p0 + q * 4 + r] = part[r] + db2v;
        }
    }
}

extern "C" void kernel_launch(void* const* d_in, const int* in_sizes, int n_in,
                              void* d_out, int out_size, void* d_ws, size_t ws_size,
                              hipStream_t stream) {
    const float* x    = (const float*)d_in[0];   // [N,64]
    const int*   eidx = (const int*)d_in[1];     // [2,E]
    const int*   qidx = (const int*)d_in[3];     // [2,P]
    const float* w1   = (const float*)d_in[4];
    const float* b1   = (const float*)d_in[5];
    const float* w2   = (const float*)d_in[6];
    const float* b2   = (const float*)d_in[7];
    const float* dw1  = (const float*)d_in[8];   // [256,64]
    const float* db1  = (const float*)d_in[9];
    const float* dw2  = (const float*)d_in[10];  // [64]
    const float* db2  = (const float*)d_in[11];  // [1]
    float* out = (float*)d_out;                  // [P]

    // ws layout (47.6 MB total, < 51.6 MB proven-safe; all 16B aligned):
    char* ws = (char*)d_ws;
    float* h0        = (float*)ws;                              // 25,600,000 B
    int*   bucketArr = (int*)(ws + 25600000);                   //  9,609,216 B
    int*   csr       = (int*)(ws + 35209216);                   // 11,210,752 B
    int*   rowptr    = (int*)(ws + 46419968);                   //    400,000 B
    int*   deg       = (int*)(ws + 46819968);                   //    400,000 B
    int*   matrix    = (int*)(ws + 47219968);                   //    400,384 B
    int*   bucketCnt = (int*)(ws + 47620352);                   //      1,564 B

    const int* src = eidx;
    const int* dst = eidx + N_EDGES;

    k0_init<<<6250, 256, 0, stream>>>((const float4*)x, (float4*)h0);
    p1a_hist<<<256, 256, 0, stream>>>(dst, matrix);
    p1b_scan<<<NB, 256, 0, stream>>>(matrix, bucketCnt);
    p1c_scatter<<<256, 256, 0, stream>>>(src, dst, x, h0, matrix, bucketArr);
    p2_build<<<NB, 256, 0, stream>>>(bucketArr, bucketCnt, csr, rowptr, deg);
    k2_agg<<<6250, 256, 0, stream>>>((const float4*)x, (float4*)h0, deg, rowptr, csr);
    k3_mlp<<<3125, 256, 0, stream>>>(h0, w1, b1, w2, b2);
    const int blocks4 = 625;
    k4_pair<<<blocks4, 256, 0, stream>>>(h0, qidx, dw1, db1, dw2, db2, out,
                                         blocks4 * 4);
}

// Round 7
// 284.597 us; speedup vs baseline: 2.1625x; 1.1827x over previous
//
#include <hip/hip_runtime.h>
#include <hip/hip_bf16.h>
#include <cstdint>

#define N_NODES 100000
#define N_EDGES 1600000
#define FDIM 64
#define NPAIRS 200000
#define NB 391          // dst buckets: ceil(100000/256)
#define BCAP 6144       // bucket entry capacity (avg 4092, ~32 sigma slack)
#define CCAP 7168       // per-bucket CSR region (padded rows fit: 6144+768)
#define EPB 6250        // edges per block in p1 passes (256 blocks)

typedef __attribute__((ext_vector_type(8))) short short8;
typedef __attribute__((ext_vector_type(4))) float floatx4;

__device__ __forceinline__ unsigned short bf16_rtne(float f) {
    unsigned u = __float_as_uint(f);
    unsigned r = (u + 0x7fffu + ((u >> 16) & 1u)) >> 16;
    return (unsigned short)r;
}

__device__ __forceinline__ void split8_rtne(const float* f, short8& hi, short8& lo) {
#pragma unroll
    for (int j = 0; j < 8; ++j) {
        unsigned short h = bf16_rtne(f[j]);
        hi[j] = (short)h;
        float hf = __uint_as_float(((unsigned)h) << 16);
        lo[j] = (short)bf16_rtne(f[j] - hf);
    }
}

__device__ __forceinline__ void split8_trunc(const float* f, short8& hi, short8& lo) {
#pragma unroll
    for (int j = 0; j < 8; ++j) {
        unsigned u = __float_as_uint(f[j]);
        hi[j] = (short)(unsigned short)(u >> 16);
        float hf = __uint_as_float(u & 0xffff0000u);
        float r = f[j] - hf;
        lo[j] = (short)(unsigned short)(__float_as_uint(r) >> 16);
    }
}

// K0: h0 = 2*x (self term of GIN with self-loop)
__global__ void k0_init(const float4* __restrict__ x4, float4* __restrict__ h04) {
    int i = blockIdx.x * blockDim.x + threadIdx.x;
    if (i < N_NODES * FDIM / 4) {
        float4 v = x4[i];
        v.x *= 2.f; v.y *= 2.f; v.z *= 2.f; v.w *= 2.f;
        h04[i] = v;
    }
}

// P1a: per-block LDS histogram of dst buckets -> matrix[block][bucket]
__global__ void __launch_bounds__(256) p1a_hist(const int* __restrict__ dst,
                                                int* __restrict__ matrix) {
    __shared__ int hist[NB];
    int tid = threadIdx.x, blk = blockIdx.x;
    for (int i = tid; i < NB; i += 256) hist[i] = 0;
    __syncthreads();
    int base = blk * EPB;
    for (int i = tid; i < EPB; i += 256) {
        int d = dst[base + i];
        atomicAdd(&hist[d >> 8], 1);
    }
    __syncthreads();
    for (int i = tid; i < NB; i += 256) matrix[blk * NB + i] = hist[i];
}

// P1b: per-bucket exclusive scan over 256 block counts (in-place) + totals.
__global__ void __launch_bounds__(256) p1b_scan(int* __restrict__ matrix,
                                                int* __restrict__ bucketCnt) {
    __shared__ int s[256];
    int b = blockIdx.x, t = threadIdx.x;
    int v = matrix[t * NB + b];
    s[t] = v;
    __syncthreads();
    for (int off = 1; off < 256; off <<= 1) {
        int u = (t >= off) ? s[t - off] : 0;
        __syncthreads();
        s[t] += u;
        __syncthreads();
    }
    matrix[t * NB + b] = s[t] - v;           // exclusive prefix
    if (t == 255) bucketCnt[b] = s[255];
}

// P1c: scatter packed (dlow<<17 | src) into bucket arrays. LDS cursors only.
__global__ void __launch_bounds__(256) p1c_scatter(const int* __restrict__ src,
        const int* __restrict__ dst, const float* __restrict__ x,
        float* __restrict__ h0, const int* __restrict__ matrix,
        int* __restrict__ bucketArr) {
    __shared__ int cur[NB];
    int tid = threadIdx.x, blk = blockIdx.x;
    for (int i = tid; i < NB; i += 256) cur[i] = matrix[blk * NB + i];
    __syncthreads();
    int base = blk * EPB;
    for (int i = tid; i < EPB; i += 256) {
        int e = base + i;
        int s = src[e], d = dst[e];
        int b = d >> 8;
        int pos = atomicAdd(&cur[b], 1);
        if (pos < BCAP) {
            bucketArr[b * BCAP + pos] = ((d & 255) << 17) | s;
        } else {
            const float* xr = x + (size_t)s * FDIM;
            float* hr = h0 + (size_t)d * FDIM;
            for (int f = 0; f < FDIM; ++f) atomicAdd(&hr[f], xr[f]);
        }
    }
}

// P2: per-bucket fine counting sort -> dense CSR (rows padded to 4 ints).
__global__ void __launch_bounds__(256) p2_build(const int* __restrict__ bucketArr,
        const int* __restrict__ bucketCnt, int* __restrict__ csr,
        int* __restrict__ rowptr, int* __restrict__ deg) {
    __shared__ int hist[256], sc[256], cur[256];
    int b = blockIdx.x, t = threadIdx.x;
    int cnt = bucketCnt[b];
    if (cnt > BCAP) cnt = BCAP;
    hist[t] = 0;
    __syncthreads();
    const int* arr = bucketArr + b * BCAP;
    for (int i = t; i < cnt; i += 256) atomicAdd(&hist[(arr[i] >> 17) & 255], 1);
    __syncthreads();
    int h = hist[t];
    int pc = (h + 3) & ~3;                   // pad row to 4 ints
    sc[t] = pc;
    __syncthreads();
    for (int off = 1; off < 256; off <<= 1) {
        int u = (t >= off) ? sc[t - off] : 0;
        __syncthreads();
        sc[t] += u;
        __syncthreads();
    }
    int rbase = sc[t] - pc;                  // exclusive padded prefix
    cur[t] = rbase;
    int n = (b << 8) + t;
    if (n < N_NODES) {
        rowptr[n] = b * CCAP + rbase;
        deg[n] = h;
    }
    __syncthreads();
    for (int i = t; i < cnt; i += 256) {
        int e = arr[i];
        int dl = (e >> 17) & 255;
        int s = e & 0x1FFFF;
        int pos = atomicAdd(&cur[dl], 1);
        csr[b * CCAP + pos] = s;
    }
}

// K2: thread per (node, float4-chunk): 16 threads/node; dense CSR; guarded
// int4 loads; 8 row-gathers in flight.
__global__ void __launch_bounds__(256) k2_agg(const float4* __restrict__ x4,
                       float4* __restrict__ h04, const int* __restrict__ deg,
                       const int* __restrict__ rowptr, const int* __restrict__ csr) {
    int gid = blockIdx.x * 256 + threadIdx.x;   // 1.6M = N*16
    int n = gid >> 4, fq = gid & 15;
    int dc = deg[n];
    const int4* srow = (const int4*)(csr + rowptr[n]);
    float4 acc = h04[(size_t)n * 16 + fq];      // 2x + overflow atomics
    for (int i = 0; i < dc; i += 8) {
        int4 s4 = srow[i >> 2];
        int4 s5;
        if (i + 4 < dc) s5 = srow[(i >> 2) + 1];
        float4 v0 = x4[(size_t)s4.x * 16 + fq];
        acc.x += v0.x; acc.y += v0.y; acc.z += v0.z; acc.w += v0.w;
        if (i + 1 < dc) {
            float4 u = x4[(size_t)s4.y * 16 + fq];
            acc.x += u.x; acc.y += u.y; acc.z += u.z; acc.w += u.w;
        }
        if (i + 2 < dc) {
            float4 u = x4[(size_t)s4.z * 16 + fq];
            acc.x += u.x; acc.y += u.y; acc.z += u.z; acc.w += u.w;
        }
        if (i + 3 < dc) {
            float4 u = x4[(size_t)s4.w * 16 + fq];
            acc.x += u.x; acc.y += u.y; acc.z += u.z; acc.w += u.w;
        }
        if (i + 4 < dc) {
            float4 u = x4[(size_t)s5.x * 16 + fq];
            acc.x += u.x; acc.y += u.y; acc.z += u.z; acc.w += u.w;
        }
        if (i + 5 < dc) {
            float4 u = x4[(size_t)s5.y * 16 + fq];
            acc.x += u.x; acc.y += u.y; acc.z += u.z; acc.w += u.w;
        }
        if (i + 6 < dc) {
            float4 u = x4[(size_t)s5.z * 16 + fq];
            acc.x += u.x; acc.y += u.y; acc.z += u.z; acc.w += u.w;
        }
        if (i + 7 < dc) {
            float4 u = x4[(size_t)s5.w * 16 + fq];
            acc.x += u.x; acc.y += u.y; acc.z += u.z; acc.w += u.w;
        }
    }
    h04[(size_t)n * 16 + fq] = acc;
}

// K3: node MLP via split-bf16 MFMA. Wave handles 16 nodes:
//   A-frags from contiguous 32B row reads (lane (q,p) = h[n0+p][q*8..+8]),
//   w1/w2 pre-split hi/lo B-frags in LDS, layer1->layer2 via padded LDS
//   transpose (stride 68: float4-aligned, only free 2-way conflicts).
// 6252 wave-slots for 6250 tasks: tail waves clamp task id, predicate store.
__global__ void __launch_bounds__(256) k3_mfma(float* __restrict__ h,
        const float* __restrict__ w1, const float* __restrict__ b1,
        const float* __restrict__ w2, const float* __restrict__ b2) {
    __shared__ short8 W1H[512], W1L[512], W2H[512], W2L[512];  // 32 KB
    __shared__ float Tbuf[4 * 16 * 68];                        // 17.4 KB
    int tid = threadIdx.x;
    for (int f = tid; f < 512; f += 256) {
        int flane = f & 63, st = f >> 6;
        int t = st & 3, s = st >> 2;
        int fq = flane >> 4, fp = flane & 15;
        int n = t * 16 + fp;
        int K0 = s * 32 + fq * 8;
        float wv[8];
#pragma unroll
        for (int j = 0; j < 8; ++j) wv[j] = w1[(K0 + j) * 64 + n];
        short8 hi, lo;
        split8_rtne(wv, hi, lo);
        W1H[f] = hi; W1L[f] = lo;
#pragma unroll
        for (int j = 0; j < 8; ++j) wv[j] = w2[(K0 + j) * 64 + n];
        split8_rtne(wv, hi, lo);
        W2H[f] = hi; W2L[f] = lo;
    }
    __syncthreads();
    int lane = tid & 63;
    int q = lane >> 4, p = lane & 15;
    int wtid0 = blockIdx.x * 4 + (tid >> 6);
    int wtid = wtid0 < 6249 ? wtid0 : 6249;
    int n0 = wtid * 16;
    float b1t[4], b2t[4];
#pragma unroll
    for (int t = 0; t < 4; ++t) {
        b1t[t] = b1[t * 16 + p];
        b2t[t] = b2[t * 16 + p];
    }
    // ---- layer 1 ----
    const float* hrow = h + (size_t)(n0 + p) * 64;
    float4 a0 = *(const float4*)(hrow + q * 8);
    float4 a1 = *(const float4*)(hrow + q * 8 + 4);
    float4 a2 = *(const float4*)(hrow + 32 + q * 8);
    float4 a3 = *(const float4*)(hrow + 32 + q * 8 + 4);
    float f0[8] = {a0.x, a0.y, a0.z, a0.w, a1.x, a1.y, a1.z, a1.w};
    float f1[8] = {a2.x, a2.y, a2.z, a2.w, a3.x, a3.y, a3.z, a3.w};
    short8 Ah0, Al0, Ah1, Al1;
    split8_trunc(f0, Ah0, Al0);
    split8_trunc(f1, Ah1, Al1);
    floatx4 acc[4];
#pragma unroll
    for (int t = 0; t < 4; ++t) acc[t] = (floatx4){0.f, 0.f, 0.f, 0.f};
#pragma unroll
    for (int t = 0; t < 4; ++t) {
        short8 bh = W1H[t * 64 + lane], bl = W1L[t * 64 + lane];
        acc[t] = __builtin_amdgcn_mfma_f32_16x16x32_bf16(Ah0, bh, acc[t], 0, 0, 0);
        acc[t] = __builtin_amdgcn_mfma_f32_16x16x32_bf16(Al0, bh, acc[t], 0, 0, 0);
        acc[t] = __builtin_amdgcn_mfma_f32_16x16x32_bf16(Ah0, bl, acc[t], 0, 0, 0);
        bh = W1H[(4 + t) * 64 + lane]; bl = W1L[(4 + t) * 64 + lane];
        acc[t] = __builtin_amdgcn_mfma_f32_16x16x32_bf16(Ah1, bh, acc[t], 0, 0, 0);
        acc[t] = __builtin_amdgcn_mfma_f32_16x16x32_bf16(Al1, bh, acc[t], 0, 0, 0);
        acc[t] = __builtin_amdgcn_mfma_f32_16x16x32_bf16(Ah1, bl, acc[t], 0, 0, 0);
    }
    // ---- ReLU + transpose through LDS (C-layout -> A-layout) ----
    float* T = Tbuf + (tid >> 6) * (16 * 68);
#pragma unroll
    for (int t = 0; t < 4; ++t) {
#pragma unroll
        for (int r = 0; r < 4; ++r)
            T[(q * 4 + r) * 68 + t * 16 + p] = fmaxf(acc[t][r] + b1t[t], 0.f);
    }
    // per-wave private region; compiler orders ds_write->ds_read via lgkmcnt
    const float* Tp = T + p * 68;
    float4 u0 = *(const float4*)(Tp + q * 8);
    float4 u1 = *(const float4*)(Tp + q * 8 + 4);
    float4 u2 = *(const float4*)(Tp + 32 + q * 8);
    float4 u3 = *(const float4*)(Tp + 32 + q * 8 + 4);
    float g0[8] = {u0.x, u0.y, u0.z, u0.w, u1.x, u1.y, u1.z, u1.w};
    float g1[8] = {u2.x, u2.y, u2.z, u2.w, u3.x, u3.y, u3.z, u3.w};
    split8_trunc(g0, Ah0, Al0);
    split8_trunc(g1, Ah1, Al1);
    // ---- layer 2 ----
#pragma unroll
    for (int t = 0; t < 4; ++t) acc[t] = (floatx4){0.f, 0.f, 0.f, 0.f};
#pragma unroll
    for (int t = 0; t < 4; ++t) {
        short8 bh = W2H[t * 64 + lane], bl = W2L[t * 64 + lane];
        acc[t] = __builtin_amdgcn_mfma_f32_16x16x32_bf16(Ah0, bh, acc[t], 0, 0, 0);
        acc[t] = __builtin_amdgcn_mfma_f32_16x16x32_bf16(Al0, bh, acc[t], 0, 0, 0);
        acc[t] = __builtin_amdgcn_mfma_f32_16x16x32_bf16(Ah0, bl, acc[t], 0, 0, 0);
        bh = W2H[(4 + t) * 64 + lane]; bl = W2L[(4 + t) * 64 + lane];
        acc[t] = __builtin_amdgcn_mfma_f32_16x16x32_bf16(Ah1, bh, acc[t], 0, 0, 0);
        acc[t] = __builtin_amdgcn_mfma_f32_16x16x32_bf16(Al1, bh, acc[t], 0, 0, 0);
        acc[t] = __builtin_amdgcn_mfma_f32_16x16x32_bf16(Ah1, bl, acc[t], 0, 0, 0);
    }
    // ---- outer ReLU + store (duplicate tail waves discard) ----
    if (wtid0 < 6250) {
#pragma unroll
        for (int t = 0; t < 4; ++t) {
#pragma unroll
            for (int r = 0; r < 4; ++r)
                h[(size_t)(n0 + q * 4 + r) * 64 + t * 16 + p] =
                    fmaxf(acc[t][r] + b2t[t], 0.f);
        }
    }
}

// K4: pair decoder via split-bf16 MFMA, 16 pairs/wave-task.
__global__ void __launch_bounds__(256) k4_pair(const float* __restrict__ h,
                        const int* __restrict__ qidx,
                        const float* __restrict__ dw1, const float* __restrict__ db1,
                        const float* __restrict__ dw2, const float* __restrict__ db2,
                        float* __restrict__ out, int numWaves) {
    __shared__ short8 BH[2048];
    __shared__ short8 BL[2048];
    int tid = threadIdx.x;
    for (int f = tid; f < 2048; f += 256) {
        int lane = f & 63, st = f >> 6;
        int t = st & 3, s = st >> 2;
        int q = lane >> 4, nl = lane & 15;
        int n = t * 16 + nl;
        int K0 = s * 32 + q * 8;
        float w[8];
#pragma unroll
        for (int j = 0; j < 8; ++j) w[j] = dw1[(K0 + j) * 64 + n];
        short8 hi, lo;
        split8_rtne(w, hi, lo);
        BH[f] = hi;
        BL[f] = lo;
    }
    __syncthreads();
    int lane = tid & 63;
    int q = lane >> 4, nl = lane & 15;
    float db1t[4], dw2t[4];
#pragma unroll
    for (int t = 0; t < 4; ++t) {
        db1t[t] = db1[t * 16 + nl];
        dw2t[t] = dw2[t * 16 + nl];
    }
    float db2v = db2[0];
    int wid = (blockIdx.x * 256 + tid) >> 6;
    for (int task = wid; task < NPAIRS / 16; task += numWaves) {
        int p0 = task * 16;
        int i1 = qidx[p0 + nl];
        int i2 = qidx[NPAIRS + p0 + nl];
        const float4* r1 = (const float4*)(h + (size_t)i1 * 64);
        const float4* r2 = (const float4*)(h + (size_t)i2 * 64);
        float4 a0 = r1[q * 2],     a1 = r1[q * 2 + 1];
        float4 b0 = r1[8 + q * 2], b1 = r1[8 + q * 2 + 1];
        float4 c0 = r2[q * 2],     c1 = r2[q * 2 + 1];
        float4 d0 = r2[8 + q * 2], d1 = r2[8 + q * 2 + 1];
        float e1a[8] = {a0.x, a0.y, a0.z, a0.w, a1.x, a1.y, a1.z, a1.w};
        float e1b[8] = {b0.x, b0.y, b0.z, b0.w, b1.x, b1.y, b1.z, b1.w};
        float e2a[8] = {c0.x, c0.y, c0.z, c0.w, c1.x, c1.y, c1.z, c1.w};
        float e2b[8] = {d0.x, d0.y, d0.z, d0.w, d1.x, d1.y, d1.z, d1.w};
        floatx4 acc[4];
#pragma unroll
        for (int t = 0; t < 4; ++t) acc[t] = (floatx4){0.f, 0.f, 0.f, 0.f};

#define DO_STEP(S, EXPR)                                                      \
        {                                                                     \
            float f8[8];                                                      \
            _Pragma("unroll")                                                 \
            for (int j = 0; j < 8; ++j) { f8[j] = (EXPR); }                   \
            short8 Ah, Al;                                                    \
            split8_trunc(f8, Ah, Al);                                         \
            _Pragma("unroll")                                                 \
            for (int t = 0; t < 4; ++t) {                                     \
                short8 bh = BH[((S) * 4 + t) * 64 + lane];                    \
                short8 bl = BL[((S) * 4 + t) * 64 + lane];                    \
                acc[t] = __builtin_amdgcn_mfma_f32_16x16x32_bf16(Ah, bh, acc[t], 0, 0, 0); \
                acc[t] = __builtin_amdgcn_mfma_f32_16x16x32_bf16(Al, bh, acc[t], 0, 0, 0); \
                acc[t] = __builtin_amdgcn_mfma_f32_16x16x32_bf16(Ah, bl, acc[t], 0, 0, 0); \
            }                                                                 \
        }

        DO_STEP(0, e1a[j] + e2a[j])
        DO_STEP(1, e1b[j] + e2b[j])
        DO_STEP(2, e1a[j] * e2a[j])
        DO_STEP(3, e1b[j] * e2b[j])
        DO_STEP(4, e1a[j])
        DO_STEP(5, e1b[j])
        DO_STEP(6, e2a[j])
        DO_STEP(7, e2b[j])
#undef DO_STEP

        float part[4] = {0.f, 0.f, 0.f, 0.f};
#pragma unroll
        for (int t = 0; t < 4; ++t) {
#pragma unroll
            for (int r = 0; r < 4; ++r)
                part[r] = fmaf(fmaxf(acc[t][r] + db1t[t], 0.f), dw2t[t], part[r]);
        }
#pragma unroll
        for (int off = 1; off < 16; off <<= 1) {
#pragma unroll
            for (int r = 0; r < 4; ++r) part[r] += __shfl_xor(part[r], off, 64);
        }
        if (nl == 0) {
#pragma unroll
            for (int r = 0; r < 4; ++r) out[p0 + q * 4 + r] = part[r] + db2v;
        }
    }
}

extern "C" void kernel_launch(void* const* d_in, const int* in_sizes, int n_in,
                              void* d_out, int out_size, void* d_ws, size_t ws_size,
                              hipStream_t stream) {
    const float* x    = (const float*)d_in[0];   // [N,64]
    const int*   eidx = (const int*)d_in[1];     // [2,E]
    const int*   qidx = (const int*)d_in[3];     // [2,P]
    const float* w1   = (const float*)d_in[4];
    const float* b1   = (const float*)d_in[5];
    const float* w2   = (const float*)d_in[6];
    const float* b2   = (const float*)d_in[7];
    const float* dw1  = (const float*)d_in[8];   // [256,64]
    const float* db1  = (const float*)d_in[9];
    const float* dw2  = (const float*)d_in[10];  // [64]
    const float* db2  = (const float*)d_in[11];  // [1]
    float* out = (float*)d_out;                  // [P]

    // ws layout (47.6 MB total; all 16B aligned):
    char* ws = (char*)d_ws;
    float* h0        = (float*)ws;                              // 25,600,000 B
    int*   bucketArr = (int*)(ws + 25600000);                   //  9,609,216 B
    int*   csr       = (int*)(ws + 35209216);                   // 11,210,752 B
    int*   rowptr    = (int*)(ws + 46419968);                   //    400,000 B
    int*   deg       = (int*)(ws + 46819968);                   //    400,000 B
    int*   matrix    = (int*)(ws + 47219968);                   //    400,384 B
    int*   bucketCnt = (int*)(ws + 47620352);                   //      1,564 B

    const int* src = eidx;
    const int* dst = eidx + N_EDGES;

    k0_init<<<6250, 256, 0, stream>>>((const float4*)x, (float4*)h0);
    p1a_hist<<<256, 256, 0, stream>>>(dst, matrix);
    p1b_scan<<<NB, 256, 0, stream>>>(matrix, bucketCnt);
    p1c_scatter<<<256, 256, 0, stream>>>(src, dst, x, h0, matrix, bucketArr);
    p2_build<<<NB, 256, 0, stream>>>(bucketArr, bucketCnt, csr, rowptr, deg);
    k2_agg<<<6250, 256, 0, stream>>>((const float4*)x, (float4*)h0, deg, rowptr, csr);
    // K3: 16 nodes/wave, 6250 tasks, 1563 blocks x 4 waves (tail clamped)
    k3_mfma<<<1563, 256, 0, stream>>>(h0, w1, b1, w2, b2);
    const int blocks4 = 625;
    k4_pair<<<blocks4, 256, 0, stream>>>(h0, qidx, dw1, db1, dw2, db2, out,
                                         blocks4 * 4);
}